// Round 4
// baseline (173.059 us; speedup 1.0000x reference)
//
#include <hip/hip_runtime.h>
#include <math.h>

// SimpleSSM: u(B,DI,L) f32, A(S), B_mat(S,DI), C_mat(DO,S), D_mat(DO,DI), h0(S)
#define BZ 8
#define DI 256
#define DS 512
#define DOUT 256
#define LL 4096
#define BS (BZ * DS)   // 4096
#define CH 64          // number of 64-wide l-chunks
#define CT 64          // chunk length
#define XST 520        // X LDS row stride in ushorts (512 + 8 pad: 8-bank spread)
#define NBLK (CH * BZ) // 512 = exactly 2 blocks/CU co-resident

typedef __bf16 bf16x8 __attribute__((ext_vector_type(8)));
typedef float f32x4 __attribute__((ext_vector_type(4)));
typedef unsigned short us8 __attribute__((ext_vector_type(8)));

__device__ __forceinline__ ushort f2b(float f) {
    union { float f; unsigned u; } v; v.f = f;
    unsigned r = v.u + 0x7FFFu + ((v.u >> 16) & 1u);
    return (ushort)(r >> 16);
}
__device__ __forceinline__ float b2f(ushort h) {
    union { unsigned u; float f; } v; v.u = ((unsigned)h) << 16;
    return v.f;
}

__device__ __forceinline__ void gload16(const void* g, ushort* l) {
    __builtin_amdgcn_global_load_lds(
        (const __attribute__((address_space(1))) unsigned int*)g,
        (__attribute__((address_space(3))) unsigned int*)l,
        16, 0, 0);
}

// ---------------------------------------------------------------------------
// k_prep: apow table + bf16 conversion of Bm/Cm + D!=0 flag. 320 blocks.
// ---------------------------------------------------------------------------
__global__ __launch_bounds__(256) void k_prep(const float* __restrict__ Au,
                                              float* __restrict__ apow,
                                              const float* __restrict__ Bm,
                                              const float* __restrict__ Cm,
                                              const float* __restrict__ Dm,
                                              ushort* __restrict__ Bmb,
                                              ushort* __restrict__ Cmb,
                                              int* __restrict__ dflag) {
    const int t = blockIdx.x * 256 + threadIdx.x;
    const int n1 = DS * DI / 4, n2 = DOUT * DS / 4, n3 = DOUT * DI / 4;
    if (t < n1) {
        float4 v = ((const float4*)Bm)[t];
        ushort4 o; o.x = f2b(v.x); o.y = f2b(v.y); o.z = f2b(v.z); o.w = f2b(v.w);
        ((ushort4*)Bmb)[t] = o;
    } else if (t < n1 + n2) {
        float4 v = ((const float4*)Cm)[t - n1];
        ushort4 o; o.x = f2b(v.x); o.y = f2b(v.y); o.z = f2b(v.z); o.w = f2b(v.w);
        ((ushort4*)Cmb)[t - n1] = o;
    } else if (t < n1 + n2 + n3) {
        float4 v = ((const float4*)Dm)[t - n1 - n2];
        if (v.x != 0.f || v.y != 0.f || v.z != 0.f || v.w != 0.f)
            atomicOr(dflag, 1);
    }
    if (t < DS) {
        float x = Au[t];
        float sp = (x > 15.f) ? x : log1pf(expf(x));
        float ad = -sp;
        float p = 1.f;
        apow[t] = 1.f;
        for (int j = 1; j <= CT; ++j) { p *= ad; apow[j * DS + t] = p; }
    }
}

// ---------------------------------------------------------------------------
// k_fused: GEMM1(Bu) + local scan + MANUAL grid barrier + carry + correction
// + GEMM2(C@Xc). Plain launch (graph-capture safe); grid NBLK=512 blocks =
// exactly 2/CU co-resident (LDS 68.6KB/block; __launch_bounds__(256,2)).
// Deadlock-free by construction: capacity (512 slots) == grid size, so every
// block is resident without waiting on any completion.
//
// Barrier protocol: after finals stores, __syncthreads (drains this block's
// stores to L2), thread0: __threadfence (device-scope release / L2 wb) ->
// agent-scope fetch_add on bar -> spin on acquire load until == NBLK
// (acquire invalidates L2 so other XCDs' finals are visible) -> __syncthreads.
// bar is memset to 0 before every launch (graph-replay safe).
//
// LDS map (bytes): X tile [64][XST=520]ush = [0,66560); crl f32[512] =
// [66560,68608). During GEMM1 the X region is dead and overlays:
//   Uc f32[32][64] dbuf @ 0 / 8192;  Bt bf16[64][40] dbuf @ 16384 / 21504.
// ---------------------------------------------------------------------------
__global__ __launch_bounds__(256, 2) void k_fused(const float* __restrict__ u,
                                                  const ushort* __restrict__ Bmb,
                                                  const ushort* __restrict__ Cmb,
                                                  const float* __restrict__ apow,
                                                  const float* __restrict__ h0,
                                                  float* __restrict__ finals,
                                                  int* __restrict__ bar,
                                                  float* __restrict__ Y) {
    __shared__ ushort smem[34304];        // 68608 B
    float* crl = (float*)&smem[33280];    // byte 66560
    const int tid = threadIdx.x;
    const int w = tid >> 6, lane = tid & 63;
    const int mrow = lane & 15, quad = lane >> 4;
    const int c0 = blockIdx.x, b = blockIdx.y;
    const int l0 = c0 * 64;

    // ---------------- GEMM1: Bu, output s(512) x l(64), K = DI ------------
    f32x4 acc1[8][4];
#pragma unroll
    for (int mi = 0; mi < 8; ++mi)
#pragma unroll
        for (int ni = 0; ni < 4; ++ni) acc1[mi][ni] = (f32x4)0.f;

    // staging: wave w stages u rows (i-local) {4w..4w+3} and {16+4w..16+4w+3}
    const int urow = w * 4 + (lane >> 4);
    const int ucol = (lane & 15) * 4;
    const float* usrc = u + ((size_t)b * DI + urow) * LL + l0 + ucol;
    const int lx = tid & 63, ig = tid >> 6;   // transpose thread mapping

    auto stageU = [&](int it) {
        const int bufu = (it & 1) * 4096;     // ushort offset (byte 0 / 8192)
        const float* s0 = usrc + (size_t)(it * 32) * LL;
        gload16(s0, smem + bufu + w * 512);
        gload16(s0 + (size_t)16 * LL, smem + bufu + w * 512 + 2048);
    };
    auto xposeU = [&](int it) {
        const float* uf = (const float*)&smem[(it & 1) * 4096];
        const int bto = 8192 + (it & 1) * 2560;   // ushort offset
        float v[8];
#pragma unroll
        for (int j = 0; j < 8; ++j) v[j] = uf[(ig * 8 + j) * 64 + lx];
        us8 o;
#pragma unroll
        for (int j = 0; j < 8; ++j) o[j] = f2b(v[j]);
        *(us8*)&smem[bto + lx * 40 + ig * 8] = o;
    };

    stageU(0);
    __syncthreads();
#pragma unroll
    for (int it = 0; it < DI / 32; ++it) {
        if (it + 1 < DI / 32) stageU(it + 1);   // async into other Uc buffer
        xposeU(it);                             // Uc[it] -> Bt[it] (f32->bf16)
        __syncthreads();                        // Bt ready; Uc[it+1] landed
        const int bto = 8192 + (it & 1) * 2560;
        bf16x8 bfr[4];
#pragma unroll
        for (int ni = 0; ni < 4; ++ni)
            bfr[ni] = *(const bf16x8*)&smem[bto + (ni * 16 + mrow) * 40 + quad * 8];
        bf16x8 af[8];
#pragma unroll
        for (int mi = 0; mi < 8; ++mi)
            af[mi] = *(const bf16x8*)&Bmb[(size_t)(128 * w + mi * 16 + mrow) * DI + it * 32 + quad * 8];
#pragma unroll
        for (int mi = 0; mi < 8; ++mi)
#pragma unroll
            for (int ni = 0; ni < 4; ++ni)
                acc1[mi][ni] = __builtin_amdgcn_mfma_f32_16x16x32_bf16(af[mi], bfr[ni], acc1[mi][ni], 0, 0, 0);
    }
    __syncthreads();   // all Bt reads done before X-store overwrites staging

    // ---------------- store acc1 -> X[l][s] (transposed store) ------------
#pragma unroll
    for (int mi = 0; mi < 8; ++mi) {
        const int sloc = 128 * w + mi * 16 + quad * 4;
#pragma unroll
        for (int ni = 0; ni < 4; ++ni) {
            const int lloc = ni * 16 + mrow;
            f32x4 v = acc1[mi][ni];
            ushort4 o; o.x = f2b(v[0]); o.y = f2b(v[1]); o.z = f2b(v[2]); o.w = f2b(v[3]);
            *(ushort4*)&smem[lloc * XST + sloc] = o;
        }
    }
    __syncthreads();

    // ---------------- local scan over l (64 steps), 2 states/thread -------
    {
        const float2 av = *(const float2*)&apow[DS + 2 * tid];
        float x0 = 0.f, x1 = 0.f;
        unsigned* p = (unsigned*)&smem[2 * tid];   // byte 4*tid
#pragma unroll 8
        for (int l = 0; l < CT; ++l) {
            unsigned v = p[l * (XST / 2)];
            x0 = av.x * x0 + b2f((ushort)(v & 0xFFFFu));
            x1 = av.y * x1 + b2f((ushort)(v >> 16));
            p[l * (XST / 2)] = (unsigned)f2b(x0) | ((unsigned)f2b(x1) << 16);
        }
        float2 fo; fo.x = x0; fo.y = x1;
        *(float2*)&finals[(size_t)c0 * BS + (size_t)b * DS + 2 * tid] = fo;
    }

    // ---------------- manual grid barrier (device-scope) ------------------
    __syncthreads();                    // all this block's finals stores drained
    if (tid == 0) {
        __threadfence();                // release: L2 writeback, device scope
        (void)__hip_atomic_fetch_add(&bar[0], 1, __ATOMIC_ACQ_REL,
                                     __HIP_MEMORY_SCOPE_AGENT);
        while (__hip_atomic_load(&bar[0], __ATOMIC_ACQUIRE,
                                 __HIP_MEMORY_SCOPE_AGENT) < NBLK)
            __builtin_amdgcn_s_sleep(2);
    }
    __syncthreads();                    // whole block waits on thread0

    // ---------------- carry for this chunk (batched-8 finals loads) -------
    {
        const float aT0 = apow[CT * DS + tid];
        const float aT1 = apow[CT * DS + 256 + tid];
        float cva = h0[tid], cvb = h0[256 + tid];
        const float* fb = finals + (size_t)b * DS;
        int c = 0;
        for (; c + 8 <= c0; c += 8) {
            float fa[8], fc[8];
#pragma unroll
            for (int j = 0; j < 8; ++j) {
                fa[j] = fb[(size_t)(c + j) * BS + tid];
                fc[j] = fb[(size_t)(c + j) * BS + 256 + tid];
            }
#pragma unroll
            for (int j = 0; j < 8; ++j) {
                cva = aT0 * cva + fa[j];
                cvb = aT1 * cvb + fc[j];
            }
        }
        for (; c < c0; ++c) {
            cva = aT0 * cva + fb[(size_t)c * BS + tid];
            cvb = aT1 * cvb + fb[(size_t)c * BS + 256 + tid];
        }
        crl[tid] = cva; crl[256 + tid] = cvb;
    }
    __syncthreads();

    // ---------------- correction: X[l][s] += apow[l+1][s] * carry[s] ------
    {
        const int lr = tid >> 2, g = tid & 3;
#pragma unroll
        for (int cc = 0; cc < 16; ++cc) {
            const int s = g * 128 + cc * 8;
            us8 x = *(const us8*)&smem[lr * XST + s];
            float4 a1 = *(const float4*)&apow[(size_t)(lr + 1) * DS + s];
            float4 a2 = *(const float4*)&apow[(size_t)(lr + 1) * DS + s + 4];
            float4 c1 = *(const float4*)&crl[s];
            float4 c2 = *(const float4*)&crl[s + 4];
            us8 o;
            o[0] = f2b(b2f(x[0]) + a1.x * c1.x);
            o[1] = f2b(b2f(x[1]) + a1.y * c1.y);
            o[2] = f2b(b2f(x[2]) + a1.z * c1.z);
            o[3] = f2b(b2f(x[3]) + a1.w * c1.w);
            o[4] = f2b(b2f(x[4]) + a2.x * c2.x);
            o[5] = f2b(b2f(x[5]) + a2.y * c2.y);
            o[6] = f2b(b2f(x[6]) + a2.z * c2.z);
            o[7] = f2b(b2f(x[7]) + a2.w * c2.w);
            *(us8*)&smem[lr * XST + s] = o;
        }
    }
    __syncthreads();

    // ---------------- GEMM2: Y = C @ Xc, output o(256) x l(64), K = DS ----
    f32x4 acc2[4][4];
#pragma unroll
    for (int mi = 0; mi < 4; ++mi)
#pragma unroll
        for (int ni = 0; ni < 4; ++ni) acc2[mi][ni] = (f32x4)0.f;

#pragma unroll
    for (int it = 0; it < DS / 32; ++it) {
        bf16x8 af2[4], bfr2[4];
#pragma unroll
        for (int mi = 0; mi < 4; ++mi)
            af2[mi] = *(const bf16x8*)&smem[(mi * 16 + mrow) * XST + it * 32 + quad * 8];
#pragma unroll
        for (int ni = 0; ni < 4; ++ni)
            bfr2[ni] = *(const bf16x8*)&Cmb[(size_t)(64 * w + ni * 16 + mrow) * DS + it * 32 + quad * 8];
#pragma unroll
        for (int mi = 0; mi < 4; ++mi)
#pragma unroll
            for (int ni = 0; ni < 4; ++ni)
                acc2[mi][ni] = __builtin_amdgcn_mfma_f32_16x16x32_bf16(af2[mi], bfr2[ni], acc2[mi][ni], 0, 0, 0);
    }

#pragma unroll
    for (int mi = 0; mi < 4; ++mi) {
        const int l = l0 + mi * 16 + quad * 4;
#pragma unroll
        for (int ni = 0; ni < 4; ++ni) {
            const int o = 64 * w + ni * 16 + mrow;
            *(float4*)&Y[((size_t)b * DOUT + o) * LL + l] = *(float4*)&acc2[mi][ni];
        }
    }
}

// ---------------------------------------------------------------------------
// k_dadd: correctness fallback Y += D @ u (D is zero for this problem; all
// blocks early-exit on dflag==0). Launched after k_fused.
// ---------------------------------------------------------------------------
__global__ __launch_bounds__(256) void k_dadd(const int* __restrict__ dflag,
                                              const float* __restrict__ Dm,
                                              const float* __restrict__ u,
                                              float* __restrict__ Y) {
    if (*dflag == 0) return;
    const int o = blockIdx.x * 16 + (threadIdx.x >> 4);
    const int li = threadIdx.x & 15;
    const int b = blockIdx.y;
    for (int lc = 0; lc < LL / 16; ++lc) {
        const int l = lc * 16 + li;
        float s = 0.f;
        for (int i = 0; i < DI; ++i)
            s += Dm[o * DI + i] * u[((size_t)b * DI + i) * LL + l];
        Y[((size_t)b * DOUT + o) * LL + l] += s;
    }
}

// ---------------------------------------------------------------------------
extern "C" void kernel_launch(void* const* d_in, const int* in_sizes, int n_in,
                              void* d_out, int out_size, void* d_ws, size_t ws_size,
                              hipStream_t stream) {
    const float* u  = (const float*)d_in[0];
    const float* Au = (const float*)d_in[1];
    const float* Bm = (const float*)d_in[2];
    const float* Cm = (const float*)d_in[3];
    const float* Dm = (const float*)d_in[4];
    const float* h0 = (const float*)d_in[5];
    float* Y = (float*)d_out;

    char* p = (char*)d_ws;
    float* finals  = (float*)p;  p += (size_t)CH * BS * 4;
    float* apow    = (float*)p;  p += (size_t)(CT + 1) * DS * 4;
    ushort* Bmb    = (ushort*)p; p += (size_t)DS * DI * 2;
    ushort* Cmb    = (ushort*)p; p += (size_t)DOUT * DS * 2;
    int* dflag     = (int*)p;    p += 64;   // dflag @ +0, bar @ +16 ints
    int* bar       = dflag + 16;

    hipMemsetAsync(dflag, 0, 128, stream);   // zero dflag + bar every launch
    k_prep<<<dim3(320), 256, 0, stream>>>(Au, apow, Bm, Cm, Dm, Bmb, Cmb, dflag);
    k_fused<<<dim3(CH, BZ), 256, 0, stream>>>(u, Bmb, Cmb, apow, h0, finals, bar, Y);
    k_dadd<<<dim3(DOUT / 16, BZ), 256, 0, stream>>>(dflag, Dm, u, Y);
}